// Round 13
// baseline (197.674 us; speedup 1.0000x reference)
//
#include <hip/hip_runtime.h>
#include <hip/hip_cooperative_groups.h>
#include <math.h>

#define HW 16384
#define W_ 128

typedef __bf16 bf16x8 __attribute__((ext_vector_type(8)));
typedef float f32x4 __attribute__((ext_vector_type(4)));
typedef float f32x2 __attribute__((ext_vector_type(2)));
typedef ushort ushortv8 __attribute__((ext_vector_type(8)));

__device__ __forceinline__ ushort f2bf(float f) {
    uint u = __builtin_bit_cast(uint, f);
    u += 0x7FFFu + ((u >> 16) & 1u);   // round-to-nearest-even
    return (ushort)(u >> 16);
}
__device__ __forceinline__ float bf2f(ushort h) {
    return __builtin_bit_cast(float, (uint)h << 16);
}

// packed 2xfp32 FMA (v_pk_fma_f32); scalar fallback if builtin missing
__device__ __forceinline__ f32x2 fma2(float w, f32x2 b, f32x2 c) {
#if defined(__has_builtin) && __has_builtin(__builtin_elementwise_fma)
    return __builtin_elementwise_fma((f32x2){w, w}, b, c);
#else
    c.x = fmaf(w, b.x, c.x); c.y = fmaf(w, b.y, c.y); return c;
#endif
}
__device__ __forceinline__ f32x2 fma2v(f32x2 a, f32x2 b, f32x2 c) {
#if defined(__has_builtin) && __has_builtin(__builtin_elementwise_fma)
    return __builtin_elementwise_fma(a, b, c);
#else
    c.x = fmaf(a.x, b.x, c.x); c.y = fmaf(a.y, b.y, c.y); return c;
#endif
}

union FragU { ushort u[8]; ushort4 h[2]; bf16x8 v; };

// ---------------------------------------------------------------------------
// 1x1 conv as bf16-MFMA GEMM + fused GN stats + fused input-GN apply.
// (used for scale1/scale2 and as the conv3 FALLBACK path)
// ---------------------------------------------------------------------------
template<int IC, int OTILE, int LOG2CG_OUT, int MODE_IN, bool IN_BF16,
         bool BF16_OUT, bool PARTS_OUT, bool ZERO_AUX>
__global__ __launch_bounds__(OTILE * 2) void conv1x1_mfma(
    const void* __restrict__ in, const float* __restrict__ statin,
    const float* __restrict__ gamma_in, const float* __restrict__ beta_in,
    const float* __restrict__ w, const float* __restrict__ bias,
    void* __restrict__ out, float* __restrict__ statout,
    float4* __restrict__ z4buf, int z4n, float* __restrict__ zfbuf, int zfn,
    long in_nstride, long out_nstride)
{
    constexpr int NT = OTILE * 2;
    constexpr int BLF = 1024 / NT;
    constexpr int BLH = 512 / NT;
    __shared__ ushort A_s[2][OTILE][36];
    __shared__ ushort B_s[2][32][132];
    __shared__ float gsum[32][2];
    __shared__ float2 ab_lds[MODE_IN ? IC : 1];
    const int tid = threadIdx.x;
    const int lane = tid & 63;
    const int wave = tid >> 6;
    const int woM = (wave >> 1) << 6;
    const int wpN = (wave & 1) << 6;
    const int lr = lane & 15;
    const int kg = (lane >> 4) << 2;
    const int n = blockIdx.z;
    const int obase = blockIdx.y * OTILE;
    const int pbase = blockIdx.x << 7;

    f32x4 acc[4][4] = {};
    float4 areg[4], bregf[BLF];
    ushortv8 bregh[BLH];

    auto issue_loads = [&](int c0) {
#pragma unroll
        for (int r = 0; r < 4; ++r) {
            int idx4 = r * NT + tid;
            int o = idx4 >> 3, kq = idx4 & 7;
            areg[r] = *(const float4*)&w[(long)(obase + o) * IC + c0 + (kq << 2)];
        }
        if (IN_BF16) {
            const ushort* inn = (const ushort*)in + (long)n * in_nstride;
#pragma unroll
            for (int r = 0; r < BLH; ++r) {
                int idx8 = r * NT + tid;
                int c = idx8 >> 4, p8 = (idx8 & 15) << 3;
                bregh[r] = *(const ushortv8*)&inn[(long)(c0 + c) * HW + pbase + p8];
            }
        } else {
            const float* inn = (const float*)in + (long)n * in_nstride;
#pragma unroll
            for (int r = 0; r < BLF; ++r) {
                int idx4 = r * NT + tid;
                int c = idx4 >> 5, p4 = (idx4 & 31) << 2;
                bregf[r] = *(const float4*)&inn[(long)(c0 + c) * HW + pbase + p4];
            }
        }
    };
    auto write_lds = [&](int c0, int buf) {
#pragma unroll
        for (int r = 0; r < 4; ++r) {
            int idx4 = r * NT + tid;
            int o = idx4 >> 3, kq = idx4 & 7;
            float4 v = areg[r];
            ushort4 h;
            h.x = f2bf(v.x); h.y = f2bf(v.y); h.z = f2bf(v.z); h.w = f2bf(v.w);
            *(ushort4*)&A_s[buf][o][kq << 2] = h;
        }
        if (IN_BF16) {
#pragma unroll
            for (int r = 0; r < BLH; ++r) {
                int idx8 = r * NT + tid;
                int c = idx8 >> 4, p8 = (idx8 & 15) << 3;
                ushortv8 hv = bregh[r];
                ushort o8[8];
                if (MODE_IN) {
                    float2 abv = ab_lds[c0 + c];
#pragma unroll
                    for (int j = 0; j < 8; ++j)
                        o8[j] = f2bf(fmaxf(fmaf(bf2f(hv[j]), abv.x, abv.y), 0.f));
                } else {
#pragma unroll
                    for (int j = 0; j < 8; ++j) o8[j] = hv[j];
                }
                ushort4 lo, hi;
                lo.x = o8[0]; lo.y = o8[1]; lo.z = o8[2]; lo.w = o8[3];
                hi.x = o8[4]; hi.y = o8[5]; hi.z = o8[6]; hi.w = o8[7];
                *(ushort4*)&B_s[buf][c][p8] = lo;
                *(ushort4*)&B_s[buf][c][p8 + 4] = hi;
            }
        } else {
#pragma unroll
            for (int r = 0; r < BLF; ++r) {
                int idx4 = r * NT + tid;
                int c = idx4 >> 5, p4 = (idx4 & 31) << 2;
                float4 v = bregf[r];
                if (MODE_IN) {
                    float2 abv = ab_lds[c0 + c];
                    v.x = fmaxf(fmaf(v.x, abv.x, abv.y), 0.f);
                    v.y = fmaxf(fmaf(v.y, abv.x, abv.y), 0.f);
                    v.z = fmaxf(fmaf(v.z, abv.x, abv.y), 0.f);
                    v.w = fmaxf(fmaf(v.w, abv.x, abv.y), 0.f);
                }
                ushort4 h;
                h.x = f2bf(v.x); h.y = f2bf(v.y); h.z = f2bf(v.z); h.w = f2bf(v.w);
                *(ushort4*)&B_s[buf][c][p4] = h;
            }
        }
    };

    issue_loads(0);
    if (tid < 32) { gsum[tid][0] = 0.f; gsum[tid][1] = 0.f; }

    if (ZERO_AUX) {
        int b = blockIdx.z * gridDim.x + blockIdx.x;
        int nb = gridDim.x * gridDim.z;
        for (int i = b * NT + tid; i < z4n; i += nb * NT)
            z4buf[i] = make_float4(0.f, 0.f, 0.f, 0.f);
        for (int i = b * NT + tid; i < zfn; i += nb * NT) zfbuf[i] = 0.f;
    }

    if (MODE_IN == 1) {
        int g = wave * 8 + (lane >> 3);
        int pl = lane & 7;
        float s = 0.f, ss = 0.f;
        for (int p = pl; p < 128; p += 8) {
            const float* pp = &statin[(((long)n * 128 + p) * 32 + g) * 2];
            s += pp[0]; ss += pp[1];
        }
        s += __shfl_xor(s, 1); ss += __shfl_xor(ss, 1);
        s += __shfl_xor(s, 2); ss += __shfl_xor(ss, 2);
        s += __shfl_xor(s, 4); ss += __shfl_xor(ss, 4);
        if (pl == 0) {
            float m = s * (1.f / 65536.f);
            float var = ss * (1.f / 65536.f) - m * m;
            float r = rsqrtf(var + 1e-5f);
#pragma unroll
            for (int j = 0; j < 4; ++j) {
                int c = g * 4 + j;
                float a = r * gamma_in[c];
                ab_lds[c] = make_float2(a, beta_in[c] - m * a);
            }
        }
        for (int c = 128 + tid; c < IC; c += NT) ab_lds[c] = make_float2(1.f, 0.f);
    } else if (MODE_IN == 2) {
        for (int c = tid; c < IC; c += NT) {
            int g = c >> 2;
            float m = statin[2 * (n * 32 + g)] * (1.f / 65536.f);
            float var = statin[2 * (n * 32 + g) + 1] * (1.f / 65536.f) - m * m;
            float r = rsqrtf(var + 1e-5f);
            float a = r * gamma_in[c];
            ab_lds[c] = make_float2(a, beta_in[c] - m * a);
        }
    }
    __syncthreads();
    write_lds(0, 0);
    issue_loads(32);
    __syncthreads();

    constexpr int NS = IC / 32;
    for (int s = 0; s < NS; ++s) {
        const int cur = s & 1;
        if (s + 1 < NS) {
            write_lds((s + 1) << 5, cur ^ 1);
            if (s + 2 < NS) issue_loads((s + 2) << 5);
        }
        FragU af[4];
#pragma unroll
        for (int mo = 0; mo < 4; ++mo) {
            const ushort* base = &A_s[cur][woM + (mo << 4) + lr][0];
            af[mo].h[0] = *(const ushort4*)(base + kg);
            af[mo].h[1] = *(const ushort4*)(base + 16 + kg);
        }
#pragma unroll
        for (int po = 0; po < 4; ++po) {
            FragU bf_;
            int p = wpN + (po << 4) + lr;
#pragma unroll
            for (int j = 0; j < 4; ++j) {
                bf_.u[j]     = B_s[cur][kg + j][p];
                bf_.u[4 + j] = B_s[cur][16 + kg + j][p];
            }
#pragma unroll
            for (int mo = 0; mo < 4; ++mo)
                acc[mo][po] = __builtin_amdgcn_mfma_f32_16x16x32_bf16(
                    af[mo].v, bf_.v, acc[mo][po], 0, 0, 0);
        }
        __syncthreads();
    }

    if (bias) {
#pragma unroll
        for (int mo = 0; mo < 4; ++mo)
#pragma unroll
            for (int r = 0; r < 4; ++r) {
                float b = bias[obase + woM + (mo << 4) + kg + r];
#pragma unroll
                for (int po = 0; po < 4; ++po) acc[mo][po][r] += b;
            }
    }

#pragma unroll
    for (int mo = 0; mo < 4; ++mo) {
        int orow0 = obase + woM + (mo << 4) + kg;
#pragma unroll
        for (int po = 0; po < 4; ++po) {
            int p = pbase + wpN + (po << 4) + lr;
            if (BF16_OUT) {
                ushort* outn = (ushort*)out + (long)n * out_nstride;
#pragma unroll
                for (int r = 0; r < 4; ++r)
                    outn[(long)(orow0 + r) * HW + p] = f2bf(acc[mo][po][r]);
            } else {
                float* outn = (float*)out + (long)n * out_nstride;
#pragma unroll
                for (int r = 0; r < 4; ++r)
                    outn[(long)(orow0 + r) * HW + p] = acc[mo][po][r];
            }
        }
    }

#pragma unroll
    for (int mo = 0; mo < 4; ++mo) {
        float s = 0.f, ss = 0.f;
#pragma unroll
        for (int po = 0; po < 4; ++po)
#pragma unroll
            for (int r = 0; r < 4; ++r) {
                float v = acc[mo][po][r];
                s += v; ss += v * v;
            }
#pragma unroll
        for (int m = 8; m >= 1; m >>= 1) {
            s  += __shfl_xor(s, m, 64);
            ss += __shfl_xor(ss, m, 64);
        }
        if (lr == 0) {
            int gt = (woM + (mo << 4) + kg) >> LOG2CG_OUT;
            atomicAdd(&gsum[gt][0], s);
            atomicAdd(&gsum[gt][1], ss);
        }
    }
    __syncthreads();
    if (PARTS_OUT) {
        if (tid < 64) {
            int g = tid >> 1, q = tid & 1;
            statout[(((long)n * 128 + blockIdx.x) * 32 + g) * 2 + q] = gsum[g][q];
        }
    } else {
        if (tid < (OTILE >> LOG2CG_OUT)) {
            int g = (obase >> LOG2CG_OUT) + tid;
            atomicAdd(&statout[2 * (n * 32 + g)],     gsum[tid][0]);
            atomicAdd(&statout[2 * (n * 32 + g) + 1], gsum[tid][1]);
        }
    }
}

// ---------------------------------------------------------------------------
// COOPERATIVE conv3 + GN3 + ReLU + residual, y3 never materialized.
// 256o x 256p tile, 1024 threads (16 waves, 4x4), grid (64,2,4)=512 blocks
// = exactly full co-residency (2 blocks/CU; LDS 70KB -> 140KB/CU).
// GEMM -> stats atomics -> grid.sync -> apply from registers.
// ---------------------------------------------------------------------------
__global__ __launch_bounds__(1024) void conv3_final_coop(
    const ushort* __restrict__ h2, const float* __restrict__ sums2,
    const float* __restrict__ g2, const float* __restrict__ b2,
    const float* __restrict__ w3, const float* __restrict__ bw3,
    const float* __restrict__ g3, const float* __restrict__ b3,
    const float* __restrict__ x, float* __restrict__ out,
    float* __restrict__ sums3)
{
    constexpr int NS = 4;   // IC=128 / 32
    __shared__ ushort A_s[2][256][36];
    __shared__ ushort B_s[2][32][264];
    __shared__ float gsum[16][2];
    __shared__ float2 ab_lds[128];
    const int tid = threadIdx.x;
    const int lane = tid & 63;
    const int wave = tid >> 6;            // 0..15
    const int woM = (wave >> 2) << 6;
    const int wpN = (wave & 3) << 6;
    const int lr = lane & 15;
    const int kg = (lane >> 4) << 2;
    const int n = blockIdx.z;
    const int obase = blockIdx.y << 8;    // 0 / 256
    const int pbase = blockIdx.x << 8;    // 256-wide p tile
    const ushort* h2n = h2 + (long)n * 128 * HW;

    f32x4 acc[4][4] = {};
    float4 areg[2];
    ushortv8 bregh;

    auto issue_loads = [&](int c0) {
#pragma unroll
        for (int r = 0; r < 2; ++r) {
            int idx4 = r * 1024 + tid;
            int o = idx4 >> 3, kq = idx4 & 7;
            areg[r] = *(const float4*)&w3[(long)(obase + o) * 128 + c0 + (kq << 2)];
        }
        {
            int c = tid >> 5, p8 = (tid & 31) << 3;
            bregh = *(const ushortv8*)&h2n[(long)(c0 + c) * HW + pbase + p8];
        }
    };
    auto write_lds = [&](int c0, int buf) {
#pragma unroll
        for (int r = 0; r < 2; ++r) {
            int idx4 = r * 1024 + tid;
            int o = idx4 >> 3, kq = idx4 & 7;
            float4 v = areg[r];
            ushort4 h;
            h.x = f2bf(v.x); h.y = f2bf(v.y); h.z = f2bf(v.z); h.w = f2bf(v.w);
            *(ushort4*)&A_s[buf][o][kq << 2] = h;
        }
        {
            int c = tid >> 5, p8 = (tid & 31) << 3;
            float2 abv = ab_lds[c0 + c];
            ushort o8[8];
#pragma unroll
            for (int j = 0; j < 8; ++j)
                o8[j] = f2bf(fmaxf(fmaf(bf2f(bregh[j]), abv.x, abv.y), 0.f));
            ushort4 lo, hi;
            lo.x = o8[0]; lo.y = o8[1]; lo.z = o8[2]; lo.w = o8[3];
            hi.x = o8[4]; hi.y = o8[5]; hi.z = o8[6]; hi.w = o8[7];
            *(ushort4*)&B_s[buf][c][p8] = lo;
            *(ushort4*)&B_s[buf][c][p8 + 4] = hi;
        }
    };

    issue_loads(0);
    if (tid < 16) { gsum[tid][0] = 0.f; gsum[tid][1] = 0.f; }
    if (tid < 128) {   // GN2 coefs (groups of 4 over 128 ch)
        int c = tid, g = c >> 2;
        float m = sums2[2 * (n * 32 + g)] * (1.f / 65536.f);
        float var = sums2[2 * (n * 32 + g) + 1] * (1.f / 65536.f) - m * m;
        float r = rsqrtf(var + 1e-5f);
        float a = r * g2[c];
        ab_lds[c] = make_float2(a, b2[c] - m * a);
    }
    __syncthreads();
    write_lds(0, 0);
    issue_loads(32);
    __syncthreads();

    for (int s = 0; s < NS; ++s) {
        const int cur = s & 1;
        if (s + 1 < NS) {
            write_lds((s + 1) << 5, cur ^ 1);
            if (s + 2 < NS) issue_loads((s + 2) << 5);
        }
        FragU af[4];
#pragma unroll
        for (int mo = 0; mo < 4; ++mo) {
            const ushort* base = &A_s[cur][woM + (mo << 4) + lr][0];
            af[mo].h[0] = *(const ushort4*)(base + kg);
            af[mo].h[1] = *(const ushort4*)(base + 16 + kg);
        }
#pragma unroll
        for (int po = 0; po < 4; ++po) {
            FragU bf_;
            int p = wpN + (po << 4) + lr;
#pragma unroll
            for (int j = 0; j < 4; ++j) {
                bf_.u[j]     = B_s[cur][kg + j][p];
                bf_.u[4 + j] = B_s[cur][16 + kg + j][p];
            }
#pragma unroll
            for (int mo = 0; mo < 4; ++mo)
                acc[mo][po] = __builtin_amdgcn_mfma_f32_16x16x32_bf16(
                    af[mo].v, bf_.v, acc[mo][po], 0, 0, 0);
        }
        __syncthreads();
    }

    // bias bw3 (included in GN stats, as in reference)
#pragma unroll
    for (int mo = 0; mo < 4; ++mo)
#pragma unroll
        for (int r = 0; r < 4; ++r) {
            float b = bw3[obase + woM + (mo << 4) + kg + r];
#pragma unroll
            for (int po = 0; po < 4; ++po) acc[mo][po][r] += b;
        }

    // GN3 partial stats (groups of 16 rows): wave-wide reduce -> LDS -> global
#pragma unroll
    for (int mo = 0; mo < 4; ++mo) {
        float s = 0.f, ss = 0.f;
#pragma unroll
        for (int po = 0; po < 4; ++po)
#pragma unroll
            for (int r = 0; r < 4; ++r) {
                float v = acc[mo][po][r];
                s += v; ss += v * v;
            }
#pragma unroll
        for (int m = 8; m >= 1; m >>= 1) {
            s  += __shfl_xor(s, m, 64);
            ss += __shfl_xor(ss, m, 64);
        }
        if (lr == 0) {
            int gt = (woM + (mo << 4)) >> 4;
            atomicAdd(&gsum[gt][0], s);
            atomicAdd(&gsum[gt][1], ss);
        }
    }
    __syncthreads();
    if (tid < 32) {
        int g = (obase >> 4) + (tid >> 1), q = tid & 1;
        atomicAdd(&sums3[2 * (n * 32 + g) + q], gsum[tid >> 1][q]);
    }

    cooperative_groups::this_grid().sync();

    // apply GN3 + ReLU + residual straight from registers
    const float cinv = 1.f / 262144.f;
    float* outn = out + (long)n * 512 * HW;
    const float* xn = x + (long)n * 512 * HW;
#pragma unroll
    for (int mo = 0; mo < 4; ++mo) {
        int g = (obase + woM + (mo << 4)) >> 4;
        float m = sums3[2 * (n * 32 + g)] * cinv;
        float var = sums3[2 * (n * 32 + g) + 1] * cinv - m * m;
        float rst = rsqrtf(var + 1e-5f);
        int orow0 = obase + woM + (mo << 4) + kg;
        float av[4], bv[4];
#pragma unroll
        for (int r = 0; r < 4; ++r) {
            av[r] = rst * g3[orow0 + r];
            bv[r] = b3[orow0 + r] - m * av[r];
        }
#pragma unroll
        for (int po = 0; po < 4; ++po) {
            int p = pbase + wpN + (po << 4) + lr;
#pragma unroll
            for (int r = 0; r < 4; ++r) {
                long off = (long)(orow0 + r) * HW + p;
                outn[off] = fmaxf(fmaf(acc[mo][po][r], av[r], bv[r]), 0.f) + xn[off];
            }
        }
    }
}

// ---------------------------------------------------------------------------
// fallback final apply (used only if cooperative occupancy check fails)
__global__ __launch_bounds__(256) void gn_final_apply_kernel(
    const ushort* __restrict__ y, const float* __restrict__ x,
    float* __restrict__ out, const float* __restrict__ sums,
    const float* __restrict__ gamma, const float* __restrict__ beta)
{
    const int n = blockIdx.z, c = blockIdx.y;
    const int ng = n * 32 + (c >> 4);
    const float cinv = 1.f / 262144.f;
    float m = sums[2 * ng] * cinv;
    float var = sums[2 * ng + 1] * cinv - m * m;
    float r = rsqrtf(var + 1e-5f);
    const float a = r * gamma[c];
    const float b = beta[c] - m * a;
    long base = (long)n * 512 * HW + (long)c * HW + (blockIdx.x << 11) + (threadIdx.x << 2);
#pragma unroll
    for (int h = 0; h < 2; ++h) {
        long off = base + h * 1024;
        ushort4 u = *(const ushort4*)&y[off];
        float4 xv = *(const float4*)&x[off];
        float4 v;
        v.x = fmaxf(fmaf(bf2f(u.x), a, b), 0.f) + xv.x;
        v.y = fmaxf(fmaf(bf2f(u.y), a, b), 0.f) + xv.y;
        v.z = fmaxf(fmaf(bf2f(u.z), a, b), 0.f) + xv.z;
        v.w = fmaxf(fmaf(bf2f(u.w), a, b), 0.f) + xv.w;
        *(float4*)&out[off] = v;
    }
}

// ---------------------------------------------------------------------------
// cata: tile 4 rows x 128 cols, 2 px/thread, packed f32x2 FMA, 16-ch chunks,
// 2 channels per barrier. GN coefs reduced from parts1 in the prologue.
// ---------------------------------------------------------------------------
#define RT 4

__device__ __forceinline__ void cata_coefs(
    const float* __restrict__ parts1, const float* __restrict__ g1,
    const float* __restrict__ b1, float2* abs_lds, int n, int c0,
    int wave, int lane)
{
    int g = (c0 >> 2) + wave;
    float s = 0.f, ss = 0.f;
#pragma unroll
    for (int p = lane; p < 128; p += 64) {
        const float* pp = &parts1[(((long)n * 128 + p) * 32 + g) * 2];
        s += pp[0]; ss += pp[1];
    }
#pragma unroll
    for (int m = 32; m >= 1; m >>= 1) {
        s += __shfl_xor(s, m, 64); ss += __shfl_xor(ss, m, 64);
    }
    if (lane == 0) {
        float m_ = s * (1.f / 65536.f);
        float var = ss * (1.f / 65536.f) - m_ * m_;
        float r = rsqrtf(var + 1e-5f);
#pragma unroll
        for (int j = 0; j < 4; ++j) {
            int c = g * 4 + j;
            float a = r * g1[c];
            abs_lds[wave * 4 + j] = make_float2(a, b1[c] - m_ * a);
        }
    }
}

__global__ __launch_bounds__(256) void cata_logits_kernel(
    const ushort* __restrict__ xd, const float* __restrict__ parts1,
    const float* __restrict__ g1, const float* __restrict__ b1,
    const float* __restrict__ wc, float* __restrict__ logits)
{
    __shared__ __align__(16) float wcs[9 * 16 * 12];
    __shared__ float xs[2][2][RT + 2][136];
    __shared__ float2 abs_lds[16];
    const int tid = threadIdx.x;
    const int r0 = blockIdx.x * RT;
    const int n = blockIdx.y;
    const int c0 = blockIdx.z << 4;
    const int qq = tid >> 7;
    const int w = tid & 127;
    const int wave = tid >> 6, lane = tid & 63;

    const bool act = tid < 96;
    const int srr = tid >> 4, sc8 = (tid & 15) << 3;
    const int sgr = r0 - 1 + srr;
    const bool inb = (unsigned)sgr < 128u;
    const ushort* xn = xd + (long)n * 256 * HW;
    ushortv8 pf0 = {}, pf1 = {};

    auto issue = [&](int cc) {
        if (act && inb) {
            pf0 = *(const ushortv8*)&xn[(long)(c0 + cc) * HW + sgr * W_ + sc8];
            pf1 = *(const ushortv8*)&xn[(long)(c0 + cc + 1) * HW + sgr * W_ + sc8];
        }
    };
    auto commit = [&](int cc, int buf) {
        if (act) {
#pragma unroll
            for (int u = 0; u < 2; ++u) {
                ushortv8 pv = u ? pf1 : pf0;
                float2 abv = abs_lds[cc + u];
                float v[8];
#pragma unroll
                for (int j = 0; j < 8; ++j)
                    v[j] = inb ? fmaxf(fmaf(bf2f(pv[j]), abv.x, abv.y), 0.f) : 0.f;
                *(float4*)&xs[buf][u][srr][4 + sc8]     = make_float4(v[0], v[1], v[2], v[3]);
                *(float4*)&xs[buf][u][srr][4 + sc8 + 4] = make_float4(v[4], v[5], v[6], v[7]);
            }
        }
    };

    cata_coefs(parts1, g1, b1, abs_lds, n, c0, wave, lane);
    for (int i = tid; i < 9 * 16 * 9; i += 256) {
        int k = i / 144, rem = i % 144, cc = rem / 9, t = rem % 9;
        wcs[(k * 16 + cc) * 12 + t] = wc[k * 1152 + (c0 + cc) * 9 + t];
    }
    if (tid < 48) {
        int b = tid / 24, u = (tid / 12) & 1, rr = (tid / 2) % 6, side = tid & 1;
        xs[b][u][rr][side ? 132 : 3] = 0.f;
    }
    __syncthreads();
    issue(0);

    f32x2 lg2[9] = {};
    for (int cc = 0; cc < 16; cc += 2) {
        int buf = (cc >> 1) & 1;
        commit(cc, buf);
        __syncthreads();
        if (cc + 2 < 16) issue(cc + 2);
#pragma unroll
        for (int u = 0; u < 2; ++u) {
            float nb[4][3];
#pragma unroll
            for (int rr = 0; rr < 4; ++rr)
#pragma unroll
                for (int dj = 0; dj < 3; ++dj)
                    nb[rr][dj] = xs[buf][u][(qq << 1) + rr][3 + w + dj];
            f32x2 np[3][3];
#pragma unroll
            for (int di = 0; di < 3; ++di)
#pragma unroll
                for (int dj = 0; dj < 3; ++dj)
                    np[di][dj] = (f32x2){nb[di][dj], nb[di + 1][dj]};
#pragma unroll
            for (int k = 0; k < 9; ++k) {
                const float* wp = &wcs[(k * 16 + cc + u) * 12];
                float4 wa = *(const float4*)wp;
                float4 wb = *(const float4*)(wp + 4);
                float w8 = wp[8];
                f32x2 s = lg2[k];
                s = fma2(wa.x, np[0][0], s); s = fma2(wa.y, np[0][1], s);
                s = fma2(wa.z, np[0][2], s); s = fma2(wa.w, np[1][0], s);
                s = fma2(wb.x, np[1][1], s); s = fma2(wb.y, np[1][2], s);
                s = fma2(wb.z, np[2][0], s); s = fma2(wb.w, np[2][1], s);
                s = fma2(w8,   np[2][2], s);
                lg2[k] = s;
            }
        }
    }
    float* lgn = logits + (long)n * 9 * HW;
    int p0 = (r0 + (qq << 1)) * W_ + w;
#pragma unroll
    for (int k = 0; k < 9; ++k) {
        atomicAdd(&lgn[(long)k * HW + p0], lg2[k].x);
        atomicAdd(&lgn[(long)k * HW + p0 + W_], lg2[k].y);
    }
}

__global__ __launch_bounds__(256) void cata_wsum_kernel(
    ushort* __restrict__ cat, const float* __restrict__ parts1,
    const float* __restrict__ g1, const float* __restrict__ b1,
    const float* __restrict__ logits)
{
    __shared__ float xs[2][2][RT + 2][136];
    __shared__ float2 abs_lds[16];
    const int tid = threadIdx.x;
    const int r0 = blockIdx.x * RT;
    const int n = blockIdx.y;
    const int c0 = blockIdx.z << 4;
    const int qq = tid >> 7;
    const int w = tid & 127;
    const int wave = tid >> 6, lane = tid & 63;

    const bool act = tid < 96;
    const int srr = tid >> 4, sc8 = (tid & 15) << 3;
    const int sgr = r0 - 1 + srr;
    const bool inb = (unsigned)sgr < 128u;
    const ushort* xn = cat + (long)n * 256 * HW;
    ushortv8 pf0 = {}, pf1 = {};

    auto issue = [&](int cc) {
        if (act && inb) {
            pf0 = *(const ushortv8*)&xn[(long)(c0 + cc) * HW + sgr * W_ + sc8];
            pf1 = *(const ushortv8*)&xn[(long)(c0 + cc + 1) * HW + sgr * W_ + sc8];
        }
    };
    auto commit = [&](int cc, int buf) {
        if (act) {
#pragma unroll
            for (int u = 0; u < 2; ++u) {
                ushortv8 pv = u ? pf1 : pf0;
                float2 abv = abs_lds[cc + u];
                float v[8];
#pragma unroll
                for (int j = 0; j < 8; ++j)
                    v[j] = inb ? fmaxf(fmaf(bf2f(pv[j]), abv.x, abv.y), 0.f) : 0.f;
                *(float4*)&xs[buf][u][srr][4 + sc8]     = make_float4(v[0], v[1], v[2], v[3]);
                *(float4*)&xs[buf][u][srr][4 + sc8 + 4] = make_float4(v[4], v[5], v[6], v[7]);
            }
        }
    };

    cata_coefs(parts1, g1, b1, abs_lds, n, c0, wave, lane);
    if (tid < 48) {
        int b = tid / 24, u = (tid / 12) & 1, rr = (tid / 2) % 6, side = tid & 1;
        xs[b][u][rr][side ? 132 : 3] = 0.f;
    }
    const float* lgn = logits + (long)n * 9 * HW;
    f32x2 filt2[9];
    {
        int p0 = (r0 + (qq << 1)) * W_ + w;
#pragma unroll
        for (int i = 0; i < 2; ++i) {
            float v[9], m = -1e30f;
#pragma unroll
            for (int k = 0; k < 9; ++k) {
                v[k] = lgn[(long)k * HW + p0 + i * W_];
                m = fmaxf(m, v[k]);
            }
            float s = 0.f;
#pragma unroll
            for (int k = 0; k < 9; ++k) { v[k] = __expf(v[k] - m); s += v[k]; }
            float inv = 1.f / s;
#pragma unroll
            for (int k = 0; k < 9; ++k) {
                if (i == 0) filt2[k].x = v[k] * inv; else filt2[k].y = v[k] * inv;
            }
        }
    }
    __syncthreads();
    issue(0);

    ushort* o1 = cat + (long)n * 256 * HW + 128L * HW;
    for (int cc = 0; cc < 16; cc += 2) {
        int buf = (cc >> 1) & 1;
        commit(cc, buf);
        __syncthreads();
        if (cc + 2 < 16) issue(cc + 2);
#pragma unroll
        for (int u = 0; u < 2; ++u) {
            float nb[4][3];
#pragma unroll
            for (int rr = 0; rr < 4; ++rr)
#pragma unroll
                for (int dj = 0; dj < 3; ++dj)
                    nb[rr][dj] = xs[buf][u][(qq << 1) + rr][3 + w + dj];
            f32x2 s2 = (f32x2){0.f, 0.f};
#pragma unroll
            for (int di = 0; di < 3; ++di)
#pragma unroll
                for (int dj = 0; dj < 3; ++dj) {
                    f32x2 np = (f32x2){nb[di][dj], nb[di + 1][dj]};
                    s2 = fma2v(filt2[di * 3 + dj], np, s2);
                }
            long ob = (long)(c0 + cc + u) * HW + (r0 + (qq << 1)) * W_ + w;
            o1[ob] = f2bf(s2.x);
            o1[ob + W_] = f2bf(s2.y);
        }
    }
}

// ---------------------------------------------------------------------------
extern "C" void kernel_launch(void* const* d_in, const int* in_sizes, int n_in,
                              void* d_out, int out_size, void* d_ws, size_t ws_size,
                              hipStream_t stream)
{
    const float* x   = (const float*)d_in[0];
    const float* w1  = (const float*)d_in[1];
    const float* g1  = (const float*)d_in[2];
    const float* b1  = (const float*)d_in[3];
    const float* wc  = (const float*)d_in[4];
    const float* w2  = (const float*)d_in[5];
    const float* bw2 = (const float*)d_in[6];
    const float* g2  = (const float*)d_in[7];
    const float* b2  = (const float*)d_in[8];
    const float* w3  = (const float*)d_in[9];
    const float* bw3 = (const float*)d_in[10];
    const float* g3  = (const float*)d_in[11];
    const float* b3  = (const float*)d_in[12];
    float* out = (float*)d_out;

    ushort* cat   = (ushort*)d_ws;                    // [4][256][HW] bf16 32MB
    ushort* h2    = cat + (long)4 * 256 * HW;         // [4][128][HW] bf16 16MB
    ushort* y3    = h2 + (long)4 * 128 * HW;          // [4][512][HW] bf16 64MB (fallback only)
    float* sums2  = (float*)(y3 + (long)4 * 512 * HW);// 256 (zeroed by conv1)
    float* sums3  = sums2 + 256;                      // 256 (zeroed by conv1)
    float* logits = sums3 + 256;                      // [4][9][HW] fp32 (zeroed by conv1)
    float* parts1 = logits + (long)4 * 9 * HW;        // [4][128][32][2]

    const long catN = 256L * HW, hN = 128L * HW, xN = 512L * HW;

    // scale1: conv (fused deterministic partial stats; zeroes logits+sums2/3)
    conv1x1_mfma<512, 128, 2, 0, false, true, true, true>
        <<<dim3(128, 1, 4), 256, 0, stream>>>(
        x, nullptr, nullptr, nullptr, w1, nullptr, cat, parts1,
        (float4*)logits, 4 * 9 * HW / 4, sums2, 512, xN, catN);

    // cata (GN1 coefs from parts1, applied on load)
    cata_logits_kernel<<<dim3(32, 4, 8), 256, 0, stream>>>(cat, parts1, g1, b1, wc, logits);
    cata_wsum_kernel<<<dim3(32, 4, 8), 256, 0, stream>>>(cat, parts1, g1, b1, logits);

    // scale2: conv on concat (GN1 coefs from parts1 inline); h2 bf16
    conv1x1_mfma<256, 128, 2, 1, true, true, false, false>
        <<<dim3(128, 1, 4), 256, 0, stream>>>(
        cat, parts1, g1, b1, w2, bw2, h2, sums2,
        nullptr, 0, nullptr, 0, catN, hN);

    // scale3 + GN3 + residual: cooperative fusion (fallback: 2-kernel path)
    int maxb = 0;
    hipError_t qe = hipOccupancyMaxActiveBlocksPerMultiprocessor(
        &maxb, conv3_final_coop, 1024, 0);
    if (qe == hipSuccess && maxb >= 2) {
        void* cargs[] = {(void*)&h2, (void*)&sums2, (void*)&g2, (void*)&b2,
                         (void*)&w3, (void*)&bw3, (void*)&g3, (void*)&b3,
                         (void*)&x, (void*)&out, (void*)&sums3};
        hipLaunchCooperativeKernel((const void*)conv3_final_coop,
                                   dim3(64, 2, 4), dim3(1024), cargs, 0, stream);
    } else {
        conv1x1_mfma<128, 256, 4, 2, true, true, false, false>
            <<<dim3(128, 2, 4), 512, 0, stream>>>(
            h2, sums2, g2, b2, w3, bw3, y3, sums3,
            nullptr, 0, nullptr, 0, hN, xN);
        gn_final_apply_kernel<<<dim3(8, 512, 4), 256, 0, stream>>>(
            y3, x, out, sums3, g3, b3);
    }
}

// Round 15
// 190.447 us; speedup vs baseline: 1.0379x; 1.0379x over previous
//
#include <hip/hip_runtime.h>
#include <math.h>

#define HW 16384
#define W_ 128

typedef __bf16 bf16x8 __attribute__((ext_vector_type(8)));
typedef float f32x4 __attribute__((ext_vector_type(4)));
typedef float f32x2 __attribute__((ext_vector_type(2)));
typedef ushort ushortv8 __attribute__((ext_vector_type(8)));

__device__ __forceinline__ ushort f2bf(float f) {
    uint u = __builtin_bit_cast(uint, f);
    u += 0x7FFFu + ((u >> 16) & 1u);   // round-to-nearest-even
    return (ushort)(u >> 16);
}
__device__ __forceinline__ float bf2f(ushort h) {
    return __builtin_bit_cast(float, (uint)h << 16);
}

// packed 2xfp32 FMA (v_pk_fma_f32); scalar fallback if builtin missing
__device__ __forceinline__ f32x2 fma2(float w, f32x2 b, f32x2 c) {
#if defined(__has_builtin) && __has_builtin(__builtin_elementwise_fma)
    return __builtin_elementwise_fma((f32x2){w, w}, b, c);
#else
    c.x = fmaf(w, b.x, c.x); c.y = fmaf(w, b.y, c.y); return c;
#endif
}
__device__ __forceinline__ f32x2 fma2v(f32x2 a, f32x2 b, f32x2 c) {
#if defined(__has_builtin) && __has_builtin(__builtin_elementwise_fma)
    return __builtin_elementwise_fma(a, b, c);
#else
    c.x = fmaf(a.x, b.x, c.x); c.y = fmaf(a.y, b.y, c.y); return c;
#endif
}

union FragU { ushort u[8]; ushort4 h[2]; bf16x8 v; };

// ---------------------------------------------------------------------------
// 1x1 conv as bf16-MFMA GEMM + fused GN stats + fused input-GN apply.
// Block tile OTILE o x 128 p (PT=128 ALWAYS: NT=256 -> 2x2 waves 128x128;
// NT=512 -> 4x2 waves 256x128. r14 bug: PT=256 made 8 waves cover only
// half of a 256x256 tile). K-step 32, 2-step register lookahead +
// double-buffered LDS, one barrier per K-step.
// MODE_IN : 0 raw; 1 coefs from parts (c<128), identity above; 2 from sums.
// MODE_OUT: 0 store (BF16_OUT type) + stats; 1 stats ONLY (no store);
//           2 final apply from registers: out=relu(a*acc+b)+x (no stats).
// NOTE: no min-waves in __launch_bounds__ (r9: (NT,4) caps VGPR at 64, spills).
// ---------------------------------------------------------------------------
template<int IC, int OTILE, int LOG2CG_OUT, int MODE_IN, bool IN_BF16,
         bool BF16_OUT, bool PARTS_OUT, bool ZERO_AUX, int MODE_OUT>
__global__ __launch_bounds__(OTILE * 2) void conv1x1_mfma(
    const void* __restrict__ in, const float* __restrict__ statin,
    const float* __restrict__ gamma_in, const float* __restrict__ beta_in,
    const float* __restrict__ w, const float* __restrict__ bias,
    void* __restrict__ out, float* __restrict__ statout,
    const float* __restrict__ statapply, const float* __restrict__ gamma_out,
    const float* __restrict__ beta_out, const float* __restrict__ xres,
    float4* __restrict__ z4buf, int z4n, float* __restrict__ zfbuf, int zfn,
    long in_nstride, long out_nstride)
{
    constexpr int NT = OTILE * 2;
    constexpr int BLF = 1024 / NT;     // fp32 B float4 loads per thread
    constexpr int BLH = 512 / NT;      // bf16 B ushort8 loads per thread
    __shared__ ushort A_s[2][OTILE][36];
    __shared__ ushort B_s[2][32][132];
    __shared__ float gsum[32][2];
    __shared__ float2 ab_lds[MODE_IN ? IC : 1];
    const int tid = threadIdx.x;
    const int lane = tid & 63;
    const int wave = tid >> 6;
    const int woM = (wave >> 1) << 6;   // NT=256: {0,64}; NT=512: {0,64,128,192}
    const int wpN = (wave & 1) << 6;    // {0,64}
    const int lr = lane & 15;
    const int kg = (lane >> 4) << 2;
    const int n = blockIdx.z;
    const int obase = blockIdx.y * OTILE;
    const int pbase = blockIdx.x << 7;

    f32x4 acc[4][4] = {};
    float4 areg[OTILE * 32 / 4 / NT];
    ushortv8 bregh[BLH];
    float4 bregf[BLF];

    auto issue_loads = [&](int c0) {
#pragma unroll
        for (int r = 0; r < OTILE * 32 / 4 / NT; ++r) {
            int idx4 = r * NT + tid;
            int o = idx4 >> 3, kq = idx4 & 7;
            areg[r] = *(const float4*)&w[(long)(obase + o) * IC + c0 + (kq << 2)];
        }
        if (IN_BF16) {
            const ushort* inn = (const ushort*)in + (long)n * in_nstride;
#pragma unroll
            for (int r = 0; r < BLH; ++r) {
                int idx8 = r * NT + tid;
                int c = idx8 >> 4, p8 = (idx8 & 15) << 3;
                bregh[r] = *(const ushortv8*)&inn[(long)(c0 + c) * HW + pbase + p8];
            }
        } else {
            const float* inn = (const float*)in + (long)n * in_nstride;
#pragma unroll
            for (int r = 0; r < BLF; ++r) {
                int idx4 = r * NT + tid;
                int c = idx4 >> 5, p4 = (idx4 & 31) << 2;
                bregf[r] = *(const float4*)&inn[(long)(c0 + c) * HW + pbase + p4];
            }
        }
    };
    auto write_lds = [&](int c0, int buf) {
#pragma unroll
        for (int r = 0; r < OTILE * 32 / 4 / NT; ++r) {
            int idx4 = r * NT + tid;
            int o = idx4 >> 3, kq = idx4 & 7;
            float4 v = areg[r];
            ushort4 h;
            h.x = f2bf(v.x); h.y = f2bf(v.y); h.z = f2bf(v.z); h.w = f2bf(v.w);
            *(ushort4*)&A_s[buf][o][kq << 2] = h;
        }
        if (IN_BF16) {
#pragma unroll
            for (int r = 0; r < BLH; ++r) {
                int idx8 = r * NT + tid;
                int c = idx8 >> 4, p8 = (idx8 & 15) << 3;
                ushortv8 hv = bregh[r];
                ushort o8[8];
                if (MODE_IN) {
                    float2 abv = ab_lds[c0 + c];
#pragma unroll
                    for (int j = 0; j < 8; ++j)
                        o8[j] = f2bf(fmaxf(fmaf(bf2f(hv[j]), abv.x, abv.y), 0.f));
                } else {
#pragma unroll
                    for (int j = 0; j < 8; ++j) o8[j] = hv[j];
                }
                ushort4 lo, hi;
                lo.x = o8[0]; lo.y = o8[1]; lo.z = o8[2]; lo.w = o8[3];
                hi.x = o8[4]; hi.y = o8[5]; hi.z = o8[6]; hi.w = o8[7];
                *(ushort4*)&B_s[buf][c][p8] = lo;
                *(ushort4*)&B_s[buf][c][p8 + 4] = hi;
            }
        } else {
#pragma unroll
            for (int r = 0; r < BLF; ++r) {
                int idx4 = r * NT + tid;
                int c = idx4 >> 5, p4 = (idx4 & 31) << 2;
                float4 v = bregf[r];
                if (MODE_IN) {
                    float2 abv = ab_lds[c0 + c];
                    v.x = fmaxf(fmaf(v.x, abv.x, abv.y), 0.f);
                    v.y = fmaxf(fmaf(v.y, abv.x, abv.y), 0.f);
                    v.z = fmaxf(fmaf(v.z, abv.x, abv.y), 0.f);
                    v.w = fmaxf(fmaf(v.w, abv.x, abv.y), 0.f);
                }
                ushort4 h;
                h.x = f2bf(v.x); h.y = f2bf(v.y); h.z = f2bf(v.z); h.w = f2bf(v.w);
                *(ushort4*)&B_s[buf][c][p4] = h;
            }
        }
    };

    issue_loads(0);
    if (tid < 32) { gsum[tid][0] = 0.f; gsum[tid][1] = 0.f; }

    if (ZERO_AUX) {   // zero aux buffers for later kernels (stream-ordered)
        int b = blockIdx.z * gridDim.x + blockIdx.x;
        int nb = gridDim.x * gridDim.z;
        for (int i = b * NT + tid; i < z4n; i += nb * NT)
            z4buf[i] = make_float4(0.f, 0.f, 0.f, 0.f);
        for (int i = b * NT + tid; i < zfn; i += nb * NT) zfbuf[i] = 0.f;
    }

    if (MODE_IN == 1) {   // coefs from parts for c<128; identity above
        int g = wave * 8 + (lane >> 3);
        int pl = lane & 7;
        if (g < 32) {
            float s = 0.f, ss = 0.f;
            for (int p = pl; p < 128; p += 8) {
                const float* pp = &statin[(((long)n * 128 + p) * 32 + g) * 2];
                s += pp[0]; ss += pp[1];
            }
            s += __shfl_xor(s, 1); ss += __shfl_xor(ss, 1);
            s += __shfl_xor(s, 2); ss += __shfl_xor(ss, 2);
            s += __shfl_xor(s, 4); ss += __shfl_xor(ss, 4);
            if (pl == 0) {
                float m = s * (1.f / 65536.f);
                float var = ss * (1.f / 65536.f) - m * m;
                float r = rsqrtf(var + 1e-5f);
#pragma unroll
                for (int j = 0; j < 4; ++j) {
                    int c = g * 4 + j;
                    float a = r * gamma_in[c];
                    ab_lds[c] = make_float2(a, beta_in[c] - m * a);
                }
            }
        }
        for (int c = 128 + tid; c < IC; c += NT) ab_lds[c] = make_float2(1.f, 0.f);
    } else if (MODE_IN == 2) {   // coefs from atomic sums, all channels
        for (int c = tid; c < IC; c += NT) {
            int g = c >> 2;
            float m = statin[2 * (n * 32 + g)] * (1.f / 65536.f);
            float var = statin[2 * (n * 32 + g) + 1] * (1.f / 65536.f) - m * m;
            float r = rsqrtf(var + 1e-5f);
            float a = r * gamma_in[c];
            ab_lds[c] = make_float2(a, beta_in[c] - m * a);
        }
    }
    __syncthreads();              // ab_lds/gsum visible
    write_lds(0, 0);
    issue_loads(32);
    __syncthreads();              // buf0 visible

    constexpr int NS = IC / 32;
    for (int s = 0; s < NS; ++s) {
        const int cur = s & 1;
        if (s + 1 < NS) {
            write_lds((s + 1) << 5, cur ^ 1);
            if (s + 2 < NS) issue_loads((s + 2) << 5);
        }
        FragU af[4];
#pragma unroll
        for (int mo = 0; mo < 4; ++mo) {
            const ushort* base = &A_s[cur][woM + (mo << 4) + lr][0];
            af[mo].h[0] = *(const ushort4*)(base + kg);
            af[mo].h[1] = *(const ushort4*)(base + 16 + kg);
        }
#pragma unroll
        for (int po = 0; po < 4; ++po) {
            FragU bf_;
            int p = wpN + (po << 4) + lr;
#pragma unroll
            for (int j = 0; j < 4; ++j) {
                bf_.u[j]     = B_s[cur][kg + j][p];
                bf_.u[4 + j] = B_s[cur][16 + kg + j][p];
            }
#pragma unroll
            for (int mo = 0; mo < 4; ++mo)
                acc[mo][po] = __builtin_amdgcn_mfma_f32_16x16x32_bf16(
                    af[mo].v, bf_.v, acc[mo][po], 0, 0, 0);
        }
        __syncthreads();
    }

    if (bias) {
#pragma unroll
        for (int mo = 0; mo < 4; ++mo)
#pragma unroll
            for (int r = 0; r < 4; ++r) {
                float b = bias[obase + woM + (mo << 4) + kg + r];
#pragma unroll
                for (int po = 0; po < 4; ++po) acc[mo][po][r] += b;
            }
    }

    if (MODE_OUT == 0) {   // plain store
#pragma unroll
        for (int mo = 0; mo < 4; ++mo) {
            int orow0 = obase + woM + (mo << 4) + kg;
#pragma unroll
            for (int po = 0; po < 4; ++po) {
                int p = pbase + wpN + (po << 4) + lr;
                if (BF16_OUT) {
                    ushort* outn = (ushort*)out + (long)n * out_nstride;
#pragma unroll
                    for (int r = 0; r < 4; ++r)
                        outn[(long)(orow0 + r) * HW + p] = f2bf(acc[mo][po][r]);
                } else {
                    float* outn = (float*)out + (long)n * out_nstride;
#pragma unroll
                    for (int r = 0; r < 4; ++r)
                        outn[(long)(orow0 + r) * HW + p] = acc[mo][po][r];
                }
            }
        }
    } else if (MODE_OUT == 2) {   // final GN apply + ReLU + residual
        const float cinv = 1.f / (float)(HW << LOG2CG_OUT);
        float* outn = (float*)out + (long)n * out_nstride;
        const float* xn = xres + (long)n * out_nstride;
#pragma unroll
        for (int mo = 0; mo < 4; ++mo) {
            int row0 = obase + woM + (mo << 4);
            int g = row0 >> LOG2CG_OUT;
            float m = statapply[2 * (n * 32 + g)] * cinv;
            float var = statapply[2 * (n * 32 + g) + 1] * cinv - m * m;
            float rst = rsqrtf(var + 1e-5f);
            int orow0 = row0 + kg;
            float av[4], bv[4];
#pragma unroll
            for (int r = 0; r < 4; ++r) {
                av[r] = rst * gamma_out[orow0 + r];
                bv[r] = beta_out[orow0 + r] - m * av[r];
            }
#pragma unroll
            for (int po = 0; po < 4; ++po) {
                int p = pbase + wpN + (po << 4) + lr;
#pragma unroll
                for (int r = 0; r < 4; ++r) {
                    long off = (long)(orow0 + r) * HW + p;
                    outn[off] = fmaxf(fmaf(acc[mo][po][r], av[r], bv[r]), 0.f) + xn[off];
                }
            }
        }
    }

    if (MODE_OUT != 2) {
        // fused GN partial stats: shfl-reduce 16-lane groups -> LDS
#pragma unroll
        for (int mo = 0; mo < 4; ++mo) {
            float s = 0.f, ss = 0.f;
#pragma unroll
            for (int po = 0; po < 4; ++po)
#pragma unroll
                for (int r = 0; r < 4; ++r) {
                    float v = acc[mo][po][r];
                    s += v; ss += v * v;
                }
#pragma unroll
            for (int m = 8; m >= 1; m >>= 1) {
                s  += __shfl_xor(s, m, 64);
                ss += __shfl_xor(ss, m, 64);
            }
            if (lr == 0) {
                int gt = (woM + (mo << 4) + kg) >> LOG2CG_OUT;
                atomicAdd(&gsum[gt][0], s);
                atomicAdd(&gsum[gt][1], ss);
            }
        }
        __syncthreads();
        if (PARTS_OUT) {   // deterministic per-block partials [n][pblk][32][2]
            if (tid < 64) {
                int g = tid >> 1, q = tid & 1;
                statout[(((long)n * 128 + blockIdx.x) * 32 + g) * 2 + q] = gsum[g][q];
            }
        } else {
            if (tid < (OTILE >> LOG2CG_OUT)) {
                int g = (obase >> LOG2CG_OUT) + tid;
                atomicAdd(&statout[2 * (n * 32 + g)],     gsum[tid][0]);
                atomicAdd(&statout[2 * (n * 32 + g) + 1], gsum[tid][1]);
            }
        }
    }
}

// ---------------------------------------------------------------------------
// cata: tile 4 rows x 128 cols, 2 px/thread, packed f32x2 FMA, 16-ch chunks,
// 2 channels per barrier. GN coefs reduced from parts1 in the prologue.
// ---------------------------------------------------------------------------
#define RT 4

__device__ __forceinline__ void cata_coefs(
    const float* __restrict__ parts1, const float* __restrict__ g1,
    const float* __restrict__ b1, float2* abs_lds, int n, int c0,
    int wave, int lane)
{
    int g = (c0 >> 2) + wave;
    float s = 0.f, ss = 0.f;
#pragma unroll
    for (int p = lane; p < 128; p += 64) {
        const float* pp = &parts1[(((long)n * 128 + p) * 32 + g) * 2];
        s += pp[0]; ss += pp[1];
    }
#pragma unroll
    for (int m = 32; m >= 1; m >>= 1) {
        s += __shfl_xor(s, m, 64); ss += __shfl_xor(ss, m, 64);
    }
    if (lane == 0) {
        float m_ = s * (1.f / 65536.f);
        float var = ss * (1.f / 65536.f) - m_ * m_;
        float r = rsqrtf(var + 1e-5f);
#pragma unroll
        for (int j = 0; j < 4; ++j) {
            int c = g * 4 + j;
            float a = r * g1[c];
            abs_lds[wave * 4 + j] = make_float2(a, b1[c] - m_ * a);
        }
    }
}

__global__ __launch_bounds__(256) void cata_logits_kernel(
    const ushort* __restrict__ xd, const float* __restrict__ parts1,
    const float* __restrict__ g1, const float* __restrict__ b1,
    const float* __restrict__ wc, float* __restrict__ logits)
{
    __shared__ __align__(16) float wcs[9 * 16 * 12];
    __shared__ float xs[2][2][RT + 2][136];
    __shared__ float2 abs_lds[16];
    const int tid = threadIdx.x;
    const int r0 = blockIdx.x * RT;
    const int n = blockIdx.y;
    const int c0 = blockIdx.z << 4;
    const int qq = tid >> 7;
    const int w = tid & 127;
    const int wave = tid >> 6, lane = tid & 63;

    const bool act = tid < 96;
    const int srr = tid >> 4, sc8 = (tid & 15) << 3;
    const int sgr = r0 - 1 + srr;
    const bool inb = (unsigned)sgr < 128u;
    const ushort* xn = xd + (long)n * 256 * HW;
    ushortv8 pf0 = {}, pf1 = {};

    auto issue = [&](int cc) {
        if (act && inb) {
            pf0 = *(const ushortv8*)&xn[(long)(c0 + cc) * HW + sgr * W_ + sc8];
            pf1 = *(const ushortv8*)&xn[(long)(c0 + cc + 1) * HW + sgr * W_ + sc8];
        }
    };
    auto commit = [&](int cc, int buf) {
        if (act) {
#pragma unroll
            for (int u = 0; u < 2; ++u) {
                ushortv8 pv = u ? pf1 : pf0;
                float2 abv = abs_lds[cc + u];
                float v[8];
#pragma unroll
                for (int j = 0; j < 8; ++j)
                    v[j] = inb ? fmaxf(fmaf(bf2f(pv[j]), abv.x, abv.y), 0.f) : 0.f;
                *(float4*)&xs[buf][u][srr][4 + sc8]     = make_float4(v[0], v[1], v[2], v[3]);
                *(float4*)&xs[buf][u][srr][4 + sc8 + 4] = make_float4(v[4], v[5], v[6], v[7]);
            }
        }
    };

    cata_coefs(parts1, g1, b1, abs_lds, n, c0, wave, lane);
    for (int i = tid; i < 9 * 16 * 9; i += 256) {
        int k = i / 144, rem = i % 144, cc = rem / 9, t = rem % 9;
        wcs[(k * 16 + cc) * 12 + t] = wc[k * 1152 + (c0 + cc) * 9 + t];
    }
    if (tid < 48) {
        int b = tid / 24, u = (tid / 12) & 1, rr = (tid / 2) % 6, side = tid & 1;
        xs[b][u][rr][side ? 132 : 3] = 0.f;
    }
    __syncthreads();
    issue(0);

    f32x2 lg2[9] = {};
    for (int cc = 0; cc < 16; cc += 2) {
        int buf = (cc >> 1) & 1;
        commit(cc, buf);
        __syncthreads();
        if (cc + 2 < 16) issue(cc + 2);
#pragma unroll
        for (int u = 0; u < 2; ++u) {
            float nb[4][3];
#pragma unroll
            for (int rr = 0; rr < 4; ++rr)
#pragma unroll
                for (int dj = 0; dj < 3; ++dj)
                    nb[rr][dj] = xs[buf][u][(qq << 1) + rr][3 + w + dj];
            f32x2 np[3][3];
#pragma unroll
            for (int di = 0; di < 3; ++di)
#pragma unroll
                for (int dj = 0; dj < 3; ++dj)
                    np[di][dj] = (f32x2){nb[di][dj], nb[di + 1][dj]};
#pragma unroll
            for (int k = 0; k < 9; ++k) {
                const float* wp = &wcs[(k * 16 + cc + u) * 12];
                float4 wa = *(const float4*)wp;
                float4 wb = *(const float4*)(wp + 4);
                float w8 = wp[8];
                f32x2 s = lg2[k];
                s = fma2(wa.x, np[0][0], s); s = fma2(wa.y, np[0][1], s);
                s = fma2(wa.z, np[0][2], s); s = fma2(wa.w, np[1][0], s);
                s = fma2(wb.x, np[1][1], s); s = fma2(wb.y, np[1][2], s);
                s = fma2(wb.z, np[2][0], s); s = fma2(wb.w, np[2][1], s);
                s = fma2(w8,   np[2][2], s);
                lg2[k] = s;
            }
        }
    }
    float* lgn = logits + (long)n * 9 * HW;
    int p0 = (r0 + (qq << 1)) * W_ + w;
#pragma unroll
    for (int k = 0; k < 9; ++k) {
        atomicAdd(&lgn[(long)k * HW + p0], lg2[k].x);
        atomicAdd(&lgn[(long)k * HW + p0 + W_], lg2[k].y);
    }
}

__global__ __launch_bounds__(256) void cata_wsum_kernel(
    ushort* __restrict__ cat, const float* __restrict__ parts1,
    const float* __restrict__ g1, const float* __restrict__ b1,
    const float* __restrict__ logits)
{
    __shared__ float xs[2][2][RT + 2][136];
    __shared__ float2 abs_lds[16];
    const int tid = threadIdx.x;
    const int r0 = blockIdx.x * RT;
    const int n = blockIdx.y;
    const int c0 = blockIdx.z << 4;
    const int qq = tid >> 7;
    const int w = tid & 127;
    const int wave = tid >> 6, lane = tid & 63;

    const bool act = tid < 96;
    const int srr = tid >> 4, sc8 = (tid & 15) << 3;
    const int sgr = r0 - 1 + srr;
    const bool inb = (unsigned)sgr < 128u;
    const ushort* xn = cat + (long)n * 256 * HW;
    ushortv8 pf0 = {}, pf1 = {};

    auto issue = [&](int cc) {
        if (act && inb) {
            pf0 = *(const ushortv8*)&xn[(long)(c0 + cc) * HW + sgr * W_ + sc8];
            pf1 = *(const ushortv8*)&xn[(long)(c0 + cc + 1) * HW + sgr * W_ + sc8];
        }
    };
    auto commit = [&](int cc, int buf) {
        if (act) {
#pragma unroll
            for (int u = 0; u < 2; ++u) {
                ushortv8 pv = u ? pf1 : pf0;
                float2 abv = abs_lds[cc + u];
                float v[8];
#pragma unroll
                for (int j = 0; j < 8; ++j)
                    v[j] = inb ? fmaxf(fmaf(bf2f(pv[j]), abv.x, abv.y), 0.f) : 0.f;
                *(float4*)&xs[buf][u][srr][4 + sc8]     = make_float4(v[0], v[1], v[2], v[3]);
                *(float4*)&xs[buf][u][srr][4 + sc8 + 4] = make_float4(v[4], v[5], v[6], v[7]);
            }
        }
    };

    cata_coefs(parts1, g1, b1, abs_lds, n, c0, wave, lane);
    if (tid < 48) {
        int b = tid / 24, u = (tid / 12) & 1, rr = (tid / 2) % 6, side = tid & 1;
        xs[b][u][rr][side ? 132 : 3] = 0.f;
    }
    const float* lgn = logits + (long)n * 9 * HW;
    f32x2 filt2[9];
    {
        int p0 = (r0 + (qq << 1)) * W_ + w;
#pragma unroll
        for (int i = 0; i < 2; ++i) {
            float v[9], m = -1e30f;
#pragma unroll
            for (int k = 0; k < 9; ++k) {
                v[k] = lgn[(long)k * HW + p0 + i * W_];
                m = fmaxf(m, v[k]);
            }
            float s = 0.f;
#pragma unroll
            for (int k = 0; k < 9; ++k) { v[k] = __expf(v[k] - m); s += v[k]; }
            float inv = 1.f / s;
#pragma unroll
            for (int k = 0; k < 9; ++k) {
                if (i == 0) filt2[k].x = v[k] * inv; else filt2[k].y = v[k] * inv;
            }
        }
    }
    __syncthreads();
    issue(0);

    ushort* o1 = cat + (long)n * 256 * HW + 128L * HW;
    for (int cc = 0; cc < 16; cc += 2) {
        int buf = (cc >> 1) & 1;
        commit(cc, buf);
        __syncthreads();
        if (cc + 2 < 16) issue(cc + 2);
#pragma unroll
        for (int u = 0; u < 2; ++u) {
            float nb[4][3];
#pragma unroll
            for (int rr = 0; rr < 4; ++rr)
#pragma unroll
                for (int dj = 0; dj < 3; ++dj)
                    nb[rr][dj] = xs[buf][u][(qq << 1) + rr][3 + w + dj];
            f32x2 s2 = (f32x2){0.f, 0.f};
#pragma unroll
            for (int di = 0; di < 3; ++di)
#pragma unroll
                for (int dj = 0; dj < 3; ++dj) {
                    f32x2 np = (f32x2){nb[di][dj], nb[di + 1][dj]};
                    s2 = fma2v(filt2[di * 3 + dj], np, s2);
                }
            long ob = (long)(c0 + cc + u) * HW + (r0 + (qq << 1)) * W_ + w;
            o1[ob] = f2bf(s2.x);
            o1[ob + W_] = f2bf(s2.y);
        }
    }
}

// ---------------------------------------------------------------------------
extern "C" void kernel_launch(void* const* d_in, const int* in_sizes, int n_in,
                              void* d_out, int out_size, void* d_ws, size_t ws_size,
                              hipStream_t stream)
{
    const float* x   = (const float*)d_in[0];
    const float* w1  = (const float*)d_in[1];
    const float* g1  = (const float*)d_in[2];
    const float* b1  = (const float*)d_in[3];
    const float* wc  = (const float*)d_in[4];
    const float* w2  = (const float*)d_in[5];
    const float* bw2 = (const float*)d_in[6];
    const float* g2  = (const float*)d_in[7];
    const float* b2  = (const float*)d_in[8];
    const float* w3  = (const float*)d_in[9];
    const float* bw3 = (const float*)d_in[10];
    const float* g3  = (const float*)d_in[11];
    const float* b3  = (const float*)d_in[12];
    float* out = (float*)d_out;

    ushort* cat   = (ushort*)d_ws;                    // [4][256][HW] bf16 32MB
    ushort* h2    = cat + (long)4 * 256 * HW;         // [4][128][HW] bf16 16MB
    float* sums2  = (float*)(h2 + (long)4 * 128 * HW);// 256 (zeroed by conv1)
    float* sums3  = sums2 + 256;                      // 256 (zeroed by conv1)
    float* logits = sums3 + 256;                      // [4][9][HW] fp32 (zeroed by conv1)
    float* parts1 = logits + (long)4 * 9 * HW;        // [4][128][32][2]

    const long catN = 256L * HW, hN = 128L * HW, xN = 512L * HW;

    // scale1: conv (fused deterministic partial stats; zeroes logits+sums2/3)
    conv1x1_mfma<512, 128, 2, 0, false, true, true, true, 0>
        <<<dim3(128, 1, 4), 256, 0, stream>>>(
        x, nullptr, nullptr, nullptr, w1, nullptr, cat, parts1,
        nullptr, nullptr, nullptr, nullptr,
        (float4*)logits, 4 * 9 * HW / 4, sums2, 512, xN, catN);

    // cata (GN1 coefs from parts1, applied on load)
    cata_logits_kernel<<<dim3(32, 4, 8), 256, 0, stream>>>(cat, parts1, g1, b1, wc, logits);
    cata_wsum_kernel<<<dim3(32, 4, 8), 256, 0, stream>>>(cat, parts1, g1, b1, logits);

    // scale2: conv on concat (GN1 coefs from parts1 inline); h2 bf16
    conv1x1_mfma<256, 128, 2, 1, true, true, false, false, 0>
        <<<dim3(128, 1, 4), 256, 0, stream>>>(
        cat, parts1, g1, b1, w2, bw2, h2, sums2,
        nullptr, nullptr, nullptr, nullptr,
        nullptr, 0, nullptr, 0, catN, hN);

    // scale3 pass 1: GEMM + bias -> GN3 stats ONLY (no output write)
    // 256o x 128p tile (r12/13-verified geometry), grid (128,2,4)
    conv1x1_mfma<128, 256, 4, 2, true, true, false, false, 1>
        <<<dim3(128, 2, 4), 512, 0, stream>>>(
        h2, sums2, g2, b2, w3, bw3, nullptr, sums3,
        nullptr, nullptr, nullptr, nullptr,
        nullptr, 0, nullptr, 0, hN, xN);

    // scale3 pass 2: redo GEMM -> apply GN3+ReLU+residual from registers
    conv1x1_mfma<128, 256, 4, 2, true, true, false, false, 2>
        <<<dim3(128, 2, 4), 512, 0, stream>>>(
        h2, sums2, g2, b2, w3, bw3, out, nullptr,
        sums3, g3, b3, x,
        nullptr, 0, nullptr, 0, hN, xN);
}